// Round 2
// baseline (203.916 us; speedup 1.0000x reference)
//
#include <hip/hip_runtime.h>

// Skeleton forward kinematics: angles [B,16,6] f32, xyz [1,16,3] f32 -> out [B,16,3] f32.
// R2: prefetch all 24 float4 of input per thread up-front (24-deep MLP), store each
// joint's position immediately (no 48-reg output buffer).

namespace {

constexpr int NJ = 16;

__device__ __forceinline__ void rot6d(const float* __restrict__ a, float R[9]) {
    float inv1 = rsqrtf(a[0]*a[0] + a[1]*a[1] + a[2]*a[2]);
    float b10 = a[0]*inv1, b11 = a[1]*inv1, b12 = a[2]*inv1;
    float d = b10*a[3] + b11*a[4] + b12*a[5];
    float c0 = a[3] - d*b10, c1 = a[4] - d*b11, c2 = a[5] - d*b12;
    float inv2 = rsqrtf(c0*c0 + c1*c1 + c2*c2);
    float b20 = c0*inv2, b21 = c1*inv2, b22 = c2*inv2;
    R[0] = b10; R[1] = b11; R[2] = b12;
    R[3] = b20; R[4] = b21; R[5] = b22;
    R[6] = b11*b22 - b12*b21;
    R[7] = b12*b20 - b10*b22;
    R[8] = b10*b21 - b11*b20;
}

__global__ __launch_bounds__(256) void skel_kernel(
    const float* __restrict__ angles,
    const float* __restrict__ xyz,
    float* __restrict__ out,
    int batch)
{
    const int b = blockIdx.x * 256 + threadIdx.x;
    if (b >= batch) return;

    // ---- prefetch: 24 independent float4 loads (full 384 B of this element) ----
    const float4* a4 = (const float4*)(angles + (size_t)b * (NJ * 6));
    float af[NJ * 6];
#pragma unroll
    for (int k = 0; k < 24; ++k) {
        float4 v = a4[k];
        af[4*k + 0] = v.x; af[4*k + 1] = v.y; af[4*k + 2] = v.z; af[4*k + 3] = v.w;
    }

    float* ob = out + (size_t)b * (NJ * 3);

    float R[9], Rw[9], pw[3], Rw3[9], pw3[3];

    // ---- joint 0 ----
    rot6d(&af[0], Rw);
    {
        float x = xyz[0], y = xyz[1], z = xyz[2];
        pw[0] = Rw[0]*x + Rw[1]*y + Rw[2]*z;
        pw[1] = Rw[3]*x + Rw[4]*y + Rw[5]*z;
        pw[2] = Rw[6]*x + Rw[7]*y + Rw[8]*z;
    }
    ob[0] = pw[0]; ob[1] = pw[1]; ob[2] = pw[2];

    // tree edges (parent -> child = e+1); chains 0-1-2-3, 3-4-5, 3-6..10, 3-11..15
    constexpr int PAR[15] = {0, 1, 2, 3, 4, 3, 6, 7, 8, 9, 3, 11, 12, 13, 14};

#pragma unroll
    for (int e = 0; e < 15; ++e) {
        const int c = e + 1;
        const int p = PAR[e];

        if (p == 3) {  // branch restart: restore saved state at joint 3
#pragma unroll
            for (int k = 0; k < 9; ++k) Rw[k] = Rw3[k];
            pw[0] = pw3[0]; pw[1] = pw3[1]; pw[2] = pw3[2];
        }

        rot6d(&af[c * 6], R);

        // t = ref[c] - ref[p] (wave-uniform scalar loads, hoisted by compiler)
        float tx = xyz[c * 3 + 0] - xyz[p * 3 + 0];
        float ty = xyz[c * 3 + 1] - xyz[p * 3 + 1];
        float tz = xyz[c * 3 + 2] - xyz[p * 3 + 2];

        // local_t = R @ t
        float lt0 = R[0]*tx + R[1]*ty + R[2]*tz;
        float lt1 = R[3]*tx + R[4]*ty + R[5]*tz;
        float lt2 = R[6]*tx + R[7]*ty + R[8]*tz;

        // pw[c] = Rw[p] @ local_t + pw[p]
        float np0 = Rw[0]*lt0 + Rw[1]*lt1 + Rw[2]*lt2 + pw[0];
        float np1 = Rw[3]*lt0 + Rw[4]*lt1 + Rw[5]*lt2 + pw[1];
        float np2 = Rw[6]*lt0 + Rw[7]*lt1 + Rw[8]*lt2 + pw[2];

        // Rw[c] = Rw[p] @ R[c]
        float T[9];
#pragma unroll
        for (int i = 0; i < 3; ++i)
#pragma unroll
            for (int j = 0; j < 3; ++j)
                T[i*3 + j] = Rw[i*3 + 0]*R[0*3 + j]
                           + Rw[i*3 + 1]*R[1*3 + j]
                           + Rw[i*3 + 2]*R[2*3 + j];
#pragma unroll
        for (int k = 0; k < 9; ++k) Rw[k] = T[k];
        pw[0] = np0; pw[1] = np1; pw[2] = np2;

        // store immediately (fire-and-forget)
        ob[c*3 + 0] = np0; ob[c*3 + 1] = np1; ob[c*3 + 2] = np2;

        if (c == 3) {  // save branch point (children 4, 6, 11)
#pragma unroll
            for (int k = 0; k < 9; ++k) Rw3[k] = Rw[k];
            pw3[0] = pw[0]; pw3[1] = pw[1]; pw3[2] = pw[2];
        }
    }
}

} // namespace

extern "C" void kernel_launch(void* const* d_in, const int* in_sizes, int n_in,
                              void* d_out, int out_size, void* d_ws, size_t ws_size,
                              hipStream_t stream) {
    const float* angles = (const float*)d_in[0];   // [B, 16, 6] f32
    const float* xyz    = (const float*)d_in[1];   // [1, 16, 3] f32
    float* out          = (float*)d_out;           // [B, 16, 3] f32

    const int batch = in_sizes[0] / (NJ * 6);
    dim3 grid((batch + 255) / 256);
    skel_kernel<<<grid, 256, 0, stream>>>(angles, xyz, out, batch);
}

// Round 3
// 176.178 us; speedup vs baseline: 1.1574x; 1.1574x over previous
//
#include <hip/hip_runtime.h>

// Skeleton forward kinematics: angles [B,16,6] f32, xyz [1,16,3] f32 -> out [B,16,3] f32.
// R3: prefetch all 24 float4 of input per thread, then __builtin_amdgcn_sched_barrier(0)
// to FORBID the scheduler from sinking the loads into the dependence chain (R2 failure
// mode: VGPR=68 proved loads were sunk). 24-deep MLP per wave -> BW-bound.

namespace {

constexpr int NJ = 16;

__device__ __forceinline__ void rot6d(const float* __restrict__ a, float R[9]) {
    float inv1 = rsqrtf(a[0]*a[0] + a[1]*a[1] + a[2]*a[2]);
    float b10 = a[0]*inv1, b11 = a[1]*inv1, b12 = a[2]*inv1;
    float d = b10*a[3] + b11*a[4] + b12*a[5];
    float c0 = a[3] - d*b10, c1 = a[4] - d*b11, c2 = a[5] - d*b12;
    float inv2 = rsqrtf(c0*c0 + c1*c1 + c2*c2);
    float b20 = c0*inv2, b21 = c1*inv2, b22 = c2*inv2;
    R[0] = b10; R[1] = b11; R[2] = b12;
    R[3] = b20; R[4] = b21; R[5] = b22;
    R[6] = b11*b22 - b12*b21;
    R[7] = b12*b20 - b10*b22;
    R[8] = b10*b21 - b11*b20;
}

__global__ __launch_bounds__(256) void skel_kernel(
    const float* __restrict__ angles,
    const float* __restrict__ xyz,
    float* __restrict__ out,
    int batch)
{
    const int b = blockIdx.x * 256 + threadIdx.x;
    if (b >= batch) return;

    // ---- prefetch: 24 independent float4 loads (full 384 B of this element) ----
    const float4* a4 = (const float4*)(angles + (size_t)b * (NJ * 6));
    float4 v[24];
#pragma unroll
    for (int k = 0; k < 24; ++k) v[k] = a4[k];

    // Hard scheduling fence: nothing may move across. Loads above CANNOT sink
    // into the dependent chain below.
    __builtin_amdgcn_sched_barrier(0);

    float af[NJ * 6];
#pragma unroll
    for (int k = 0; k < 24; ++k) {
        af[4*k + 0] = v[k].x; af[4*k + 1] = v[k].y;
        af[4*k + 2] = v[k].z; af[4*k + 3] = v[k].w;
    }

    float* ob = out + (size_t)b * (NJ * 3);

    float R[9], Rw[9], pw[3], Rw3[9], pw3[3];

    // ---- joint 0 ----
    rot6d(&af[0], Rw);
    {
        float x = xyz[0], y = xyz[1], z = xyz[2];
        pw[0] = Rw[0]*x + Rw[1]*y + Rw[2]*z;
        pw[1] = Rw[3]*x + Rw[4]*y + Rw[5]*z;
        pw[2] = Rw[6]*x + Rw[7]*y + Rw[8]*z;
    }
    ob[0] = pw[0]; ob[1] = pw[1]; ob[2] = pw[2];

    // tree edges (parent -> child = e+1); chains 0-1-2-3, 3-4-5, 3-6..10, 3-11..15
    constexpr int PAR[15] = {0, 1, 2, 3, 4, 3, 6, 7, 8, 9, 3, 11, 12, 13, 14};

#pragma unroll
    for (int e = 0; e < 15; ++e) {
        const int c = e + 1;
        const int p = PAR[e];

        if (p == 3) {  // branch restart: restore saved state at joint 3
#pragma unroll
            for (int k = 0; k < 9; ++k) Rw[k] = Rw3[k];
            pw[0] = pw3[0]; pw[1] = pw3[1]; pw[2] = pw3[2];
        }

        rot6d(&af[c * 6], R);

        // t = ref[c] - ref[p] (wave-uniform scalar loads)
        float tx = xyz[c * 3 + 0] - xyz[p * 3 + 0];
        float ty = xyz[c * 3 + 1] - xyz[p * 3 + 1];
        float tz = xyz[c * 3 + 2] - xyz[p * 3 + 2];

        // local_t = R @ t
        float lt0 = R[0]*tx + R[1]*ty + R[2]*tz;
        float lt1 = R[3]*tx + R[4]*ty + R[5]*tz;
        float lt2 = R[6]*tx + R[7]*ty + R[8]*tz;

        // pw[c] = Rw[p] @ local_t + pw[p]
        float np0 = Rw[0]*lt0 + Rw[1]*lt1 + Rw[2]*lt2 + pw[0];
        float np1 = Rw[3]*lt0 + Rw[4]*lt1 + Rw[5]*lt2 + pw[1];
        float np2 = Rw[6]*lt0 + Rw[7]*lt1 + Rw[8]*lt2 + pw[2];

        // Rw[c] = Rw[p] @ R[c]
        float T[9];
#pragma unroll
        for (int i = 0; i < 3; ++i)
#pragma unroll
            for (int j = 0; j < 3; ++j)
                T[i*3 + j] = Rw[i*3 + 0]*R[0*3 + j]
                           + Rw[i*3 + 1]*R[1*3 + j]
                           + Rw[i*3 + 2]*R[2*3 + j];
#pragma unroll
        for (int k = 0; k < 9; ++k) Rw[k] = T[k];
        pw[0] = np0; pw[1] = np1; pw[2] = np2;

        // store immediately (fire-and-forget)
        ob[c*3 + 0] = np0; ob[c*3 + 1] = np1; ob[c*3 + 2] = np2;

        if (c == 3) {  // save branch point (children 4, 6, 11)
#pragma unroll
            for (int k = 0; k < 9; ++k) Rw3[k] = Rw[k];
            pw3[0] = pw[0]; pw3[1] = pw[1]; pw3[2] = pw[2];
        }
    }
}

} // namespace

extern "C" void kernel_launch(void* const* d_in, const int* in_sizes, int n_in,
                              void* d_out, int out_size, void* d_ws, size_t ws_size,
                              hipStream_t stream) {
    const float* angles = (const float*)d_in[0];   // [B, 16, 6] f32
    const float* xyz    = (const float*)d_in[1];   // [1, 16, 3] f32
    float* out          = (float*)d_out;           // [B, 16, 3] f32

    const int batch = in_sizes[0] / (NJ * 6);
    dim3 grid((batch + 255) / 256);
    skel_kernel<<<grid, 256, 0, stream>>>(angles, xyz, out, batch);
}